// Round 3
// baseline (272.511 us; speedup 1.0000x reference)
//
#include <hip/hip_runtime.h>
#include <hip/hip_bf16.h>

#define N_TOKENS 16384
#define DIM      2048
#define NEXP     64
#define TOPK     8
#define BK       16
#define TM       512            // tokens per block
#define APLANE   644            // 32 groups * 20 + 4 (pad -> 2-way staging writes)
#define BPLANE   100            // 8 groups * 12 + 4

// ---------------------------------------------------------------------------
// Kernel 1: router GEMM, fp32 (index stability requires fp32 logits).
// 512 tokens x 64 experts per 256-thread block; 16x8 register micro-tile
// (rc/(r+c)=5.33 -> LDS pipe ~balanced with FMA issue). LDS layouts:
//   As[kk][tg][i], group stride 20: banks 20*tg%32 = {0,20,8,28,16,4,24,12}
//     -> compute-phase b128 reads conflict-free (8 bcast lanes per addr).
//   Bs[kk][cg][j], group stride 12: banks {0,12,24,4,16,28,8,20} -> free.
//   Plane strides 644/100 spread the transposed staging writes to 2-way
//   (free per m136), killing the 3.9M conflicts of the previous version.
// K split into 16 slabs (blockIdx.y) -> 512 blocks = 2 blocks/CU.
// ---------------------------------------------------------------------------
__global__ __launch_bounds__(256, 2) void gemm_kernel(const float* __restrict__ A,
                                                      const float* __restrict__ W,
                                                      float* __restrict__ out,
                                                      int k_len) {
    __shared__ float As[BK * APLANE];
    __shared__ float Bs[BK * BPLANE];

    const int tid = threadIdx.x;
    const int tg  = tid >> 3;       // 0..31 token group (16 tokens)
    const int cg  = tid & 7;        // 0..7  expert group (8 experts)
    const int token_base = blockIdx.x * TM;
    const int k_start = blockIdx.y * k_len;
    out += (size_t)blockIdx.y * N_TOKENS * NEXP;

    float acc[16][8] = {};

    for (int k0 = k_start; k0 < k_start + k_len; k0 += BK) {
        // batch all staging loads into registers first (overlapped in flight)
        float4 av[8];
        #pragma unroll
        for (int l = 0; l < 8; ++l) {
            int slot = tid + l * 256;          // 0..2047
            int row  = slot >> 2;              // 0..511
            int kq   = (slot & 3) << 2;        // 0,4,8,12
            av[l] = *(const float4*)(A + (size_t)(token_base + row) * DIM + k0 + kq);
        }
        float4 bv;
        {
            int row = tid >> 2;                // 0..63
            int kq  = (tid & 3) << 2;
            bv = *(const float4*)(W + (size_t)row * DIM + k0 + kq);
        }

        #pragma unroll
        for (int l = 0; l < 8; ++l) {
            int slot = tid + l * 256;
            int row  = slot >> 2;
            int kq   = (slot & 3) << 2;
            float* dst = As + (row >> 4) * 20 + (row & 15);
            dst[(kq + 0) * APLANE] = av[l].x;
            dst[(kq + 1) * APLANE] = av[l].y;
            dst[(kq + 2) * APLANE] = av[l].z;
            dst[(kq + 3) * APLANE] = av[l].w;
        }
        {
            int row = tid >> 2;
            int kq  = (tid & 3) << 2;
            float* dst = Bs + (row >> 3) * 12 + (row & 7);
            dst[(kq + 0) * BPLANE] = bv.x;
            dst[(kq + 1) * BPLANE] = bv.y;
            dst[(kq + 2) * BPLANE] = bv.z;
            dst[(kq + 3) * BPLANE] = bv.w;
        }
        __syncthreads();

        #pragma unroll 4
        for (int kk = 0; kk < BK; ++kk) {
            const float* ap = As + kk * APLANE + tg * 20;
            const float* bp = Bs + kk * BPLANE + cg * 12;
            float4 a0 = *(const float4*)(ap);
            float4 a1 = *(const float4*)(ap + 4);
            float4 a2 = *(const float4*)(ap + 8);
            float4 a3 = *(const float4*)(ap + 12);
            float4 b0 = *(const float4*)(bp);
            float4 b1 = *(const float4*)(bp + 4);
            float a[16] = {a0.x, a0.y, a0.z, a0.w, a1.x, a1.y, a1.z, a1.w,
                           a2.x, a2.y, a2.z, a2.w, a3.x, a3.y, a3.z, a3.w};
            float b[8]  = {b0.x, b0.y, b0.z, b0.w, b1.x, b1.y, b1.z, b1.w};
            #pragma unroll
            for (int i = 0; i < 16; ++i)
                #pragma unroll
                for (int j = 0; j < 8; ++j)
                    acc[i][j] += a[i] * b[j];
        }
        __syncthreads();
    }

    #pragma unroll
    for (int i = 0; i < 16; ++i) {
        float* orow = out + (size_t)(token_base + tg * 16 + i) * NEXP + cg * 8;
        *(float4*)(orow)     = make_float4(acc[i][0], acc[i][1], acc[i][2], acc[i][3]);
        *(float4*)(orow + 4) = make_float4(acc[i][4], acc[i][5], acc[i][6], acc[i][7]);
    }
}

// ---------------------------------------------------------------------------
// Kernel 2: slab-sum + softmax + top-8 via rank selection (lax.top_k
// semantics: sorted desc, ties -> lower index). One token per wave-iter,
// 4096 waves. Slab loop unrolled x4 with independent partials.
// ---------------------------------------------------------------------------
__global__ __launch_bounds__(256) void topk_kernel(const float* __restrict__ logits,
                                                   int nslab,
                                                   float* __restrict__ out_w,
                                                   float* __restrict__ out_i,
                                                   float* __restrict__ cnt_ws,
                                                   float* __restrict__ sp_ws) {
    __shared__ float s_cnt[NEXP];
    __shared__ float s_sp[NEXP];
    if (threadIdx.x < NEXP) { s_cnt[threadIdx.x] = 0.f; s_sp[threadIdx.x] = 0.f; }
    __syncthreads();

    const int lane = threadIdx.x & 63;
    const int wave = blockIdx.x * 4 + (threadIdx.x >> 6);   // 0..4095
    const size_t slab_stride = (size_t)N_TOKENS * NEXP;

    float sp  = 0.f;
    float cnt = 0.f;

    for (int t = wave; t < N_TOKENS; t += 4096) {
        const float* p = logits + (size_t)t * NEXP + lane;
        float s0 = 0.f, s1 = 0.f, s2 = 0.f, s3 = 0.f;
        for (int s = 0; s < nslab; s += 4) {   // nslab in {4,8,16}
            s0 += p[(size_t)(s + 0) * slab_stride];
            s1 += p[(size_t)(s + 1) * slab_stride];
            s2 += p[(size_t)(s + 2) * slab_stride];
            s3 += p[(size_t)(s + 3) * slab_stride];
        }
        float lg = (s0 + s1) + (s2 + s3);

        // softmax over 64 lanes
        float m = lg;
        #pragma unroll
        for (int off = 32; off; off >>= 1) m = fmaxf(m, __shfl_xor(m, off));
        float e = expf(lg - m);
        float ssum = e;
        #pragma unroll
        for (int off = 32; off; off >>= 1) ssum += __shfl_xor(ssum, off);
        float score = e / ssum;
        sp += score;

        // rank of this lane's score (64 independent, pipelined shuffles)
        int rank = 0;
        #pragma unroll
        for (int j = 0; j < 64; ++j) {
            float sj = __shfl(score, j);
            rank += (sj > score) || (sj == score && j < lane);
        }
        bool sel = rank < TOPK;

        float v = sel ? score : 0.f;
        #pragma unroll
        for (int off = 32; off; off >>= 1) v += __shfl_xor(v, off);

        if (sel) {
            out_w[(size_t)t * TOPK + rank] = score / v;
            out_i[(size_t)t * TOPK + rank] = (float)lane;
            cnt += 1.f;
        }
    }

    atomicAdd(&s_sp[lane], sp);
    atomicAdd(&s_cnt[lane], cnt);
    __syncthreads();
    if (threadIdx.x < 64)       atomicAdd(&cnt_ws[threadIdx.x], s_cnt[threadIdx.x]);
    else if (threadIdx.x < 128) atomicAdd(&sp_ws[threadIdx.x - 64], s_sp[threadIdx.x - 64]);
}

// ---------------------------------------------------------------------------
// Kernel 3: aux_loss = ALPHA * E * sum_e (cnt[e]/(N*K)) * (sum_prob[e]/N)
// ---------------------------------------------------------------------------
__global__ void finalize_kernel(const float* __restrict__ cnt_ws,
                                const float* __restrict__ sp_ws,
                                float* __restrict__ out_aux) {
    int lane = threadIdx.x;
    float v = (cnt_ws[lane] / (float)(N_TOKENS * TOPK)) *
              (sp_ws[lane] / (float)N_TOKENS);
    #pragma unroll
    for (int off = 32; off; off >>= 1) v += __shfl_xor(v, off);
    if (lane == 0) out_aux[0] = 0.001f * (float)NEXP * v;
}

extern "C" void kernel_launch(void* const* d_in, const int* in_sizes, int n_in,
                              void* d_out, int out_size, void* d_ws, size_t ws_size,
                              hipStream_t stream) {
    const float* A = (const float*)d_in[0];   // hidden_states (16384 x 2048)
    const float* W = (const float*)d_in[1];   // weight        (64 x 2048)
    float* out = (float*)d_out;

    const size_t logits_elems = (size_t)N_TOKENS * NEXP;
    const size_t logits_bytes = logits_elems * sizeof(float);

    // 16 K-slabs -> 512 gemm blocks = 2/CU (grid.x is only 32 token-tiles)
    int nslab = 4;
    if (ws_size >= 16 * logits_bytes + 1024)     nslab = 16;
    else if (ws_size >= 8 * logits_bytes + 1024) nslab = 8;

    float* l0     = (float*)d_ws;
    float* cnt_ws = (float*)((char*)d_ws + (size_t)nslab * logits_bytes);
    float* sp_ws  = cnt_ws + NEXP;

    hipMemsetAsync(cnt_ws, 0, 2 * NEXP * sizeof(float), stream);

    hipLaunchKernelGGL(gemm_kernel, dim3(N_TOKENS / TM, nslab), dim3(256), 0, stream,
                       A, W, l0, DIM / nslab);

    float* out_w = out;
    float* out_i = out + (size_t)N_TOKENS * TOPK;
    float* out_a = out + 2 * (size_t)N_TOKENS * TOPK;

    hipLaunchKernelGGL(topk_kernel, dim3(1024), dim3(256), 0, stream,
                       l0, nslab, out_w, out_i, cnt_ws, sp_ws);

    hipLaunchKernelGGL(finalize_kernel, dim3(1), dim3(64), 0, stream,
                       cnt_ws, sp_ws, out_a);
}